// Round 1
// baseline (120.900 us; speedup 1.0000x reference)
//
#include <hip/hip_runtime.h>
#include <math.h>

// Attn: out = softmax(tanh(Q) @ H^T) @ H ; B=8, Q=2048, K=2048, Hdim=128, fp32 in/out.
// R3: one-shot f16 prep (K + K^T, XOR-swizzled) -> main kernel stages tiles with
//     global_load_lds (zero staging VALU), counted-vmcnt 4-phase pipeline with raw
//     barriers, swizzled conflict-free ds_read_b128, defer-rescale, f16 O-partials.

typedef _Float16 half8 __attribute__((ext_vector_type(8)));
typedef _Float16 half4 __attribute__((ext_vector_type(4)));
typedef float    f32x4 __attribute__((ext_vector_type(4)));

#define QQ 2048
#define KK 2048
#define HH 128
#define BM 64
#define BN 64
#define NTILES 32
#define PS_STR 72            // Ps row stride (halves): 36 dw == 4 mod 32 -> 2-way max
#define L2E 1.44269504f
#define SPLITS_TARGET 3

// prep-kernel LDS strides (padded; prep is one-shot, conflicts don't matter there)
#define KS_STRP 136
#define VT_STRP 72

// ---- workspace layout (bytes) ----
//  [0, 4MB)              Kh  f16 [B][K][H]      stored[k][h ^ ((k&7)<<3)]
//  [4MB, 8MB)            Vth f16 [B][kt][H][64] stored[h][n ^ ((h&7)<<3)]
//  [8MB, +splits*4MB)    O partials f16 (normalized by split denom)
//  then m (f32) splits*16384, then l (f32) splits*16384
#define KH_HALVES     ((size_t)8 * KK * HH)            // 2,097,152 halves per region
#define PREP_BYTES    (KH_HALVES * 4)                  // 8,388,608 B (both regions)
#define OSPLIT_BYTES  ((size_t)256 * BM * HH * 2)      // 4,194,304 B per split
#define MLSPLIT_FLOATS ((size_t)256 * BM)              // 16384 floats per split

union U32H { unsigned int u; _Float16 h[2]; };

typedef __attribute__((address_space(1))) const void gvoid;
typedef __attribute__((address_space(3))) void lvoid;

#define WAITVM4 asm volatile("s_waitcnt vmcnt(4)" ::: "memory")
#define WAITVM0 asm volatile("s_waitcnt vmcnt(0)" ::: "memory")
static __device__ __forceinline__ void wgbar() {
    asm volatile("" ::: "memory");
    __builtin_amdgcn_s_barrier();
    asm volatile("" ::: "memory");
}

// ---------------------------------------------------------------------------
// prep: history f32 -> Kh (row-major f16, swizzled) + Vth (tile-transposed f16,
// swizzled). One block per (b, kt) tile. Runs once per launch (~3-4 us).
// ---------------------------------------------------------------------------
__launch_bounds__(256)
__global__ void attn_prep(const float* __restrict__ history,
                          _Float16* __restrict__ wsh) {
    __shared__ __align__(16) _Float16 Ks[BN * KS_STRP];
    __shared__ __align__(16) _Float16 Vt[HH * VT_STRP];

    const int tid = threadIdx.x;
    const int bid = blockIdx.x;          // 256 = 8 b * 32 kt
    const int b   = bid >> 5;
    const int kt  = bid & 31;

    // stage: coalesced f32 read -> f16 LDS tile [64][128] (padded)
    const float* hb = history + ((size_t)b * KK + (size_t)kt * BN) * HH;
    const int r0 = tid >> 5;
    const int c4 = (tid & 31) * 4;
    #pragma unroll
    for (int j = 0; j < 8; ++j) {
        const float4 g = *(const float4*)(hb + (size_t)(r0 + 8 * j) * HH + c4);
        half4 hv;
        hv[0] = (_Float16)g.x; hv[1] = (_Float16)g.y;
        hv[2] = (_Float16)g.z; hv[3] = (_Float16)g.w;
        *(half4*)&Ks[(r0 + 8 * j) * KS_STRP + c4] = hv;
    }
    __syncthreads();

    // transpose into Vt via b32-pair reads (two h-rows per thread)
    {
        const int h0  = 2 * (tid & 63);
        const int n0t = (tid >> 6) * 16;
        half8 ra0, ra1, rb0, rb1;
        #pragma unroll
        for (int i = 0; i < 8; ++i) {
            U32H t; t.u = *(const unsigned int*)&Ks[(n0t + i) * KS_STRP + h0];
            ra0[i] = t.h[0]; rb0[i] = t.h[1];
        }
        #pragma unroll
        for (int i = 8; i < 16; ++i) {
            U32H t; t.u = *(const unsigned int*)&Ks[(n0t + i) * KS_STRP + h0];
            ra1[i - 8] = t.h[0]; rb1[i - 8] = t.h[1];
        }
        *(half8*)&Vt[(h0    ) * VT_STRP + n0t    ] = ra0;
        *(half8*)&Vt[(h0    ) * VT_STRP + n0t + 8] = ra1;
        *(half8*)&Vt[(h0 + 1) * VT_STRP + n0t    ] = rb0;
        *(half8*)&Vt[(h0 + 1) * VT_STRP + n0t + 8] = rb1;
    }

    // write Kh: stored[k][h ^ ((k&7)<<3)]  (reads Ks only; already sync'd)
    {
        const int k  = tid >> 2;
        const int c0 = (tid & 3) * 32;
        const int sk = (k & 7) << 3;
        _Float16* dst = wsh + ((size_t)b * KK + (size_t)kt * BN + k) * HH;
        #pragma unroll
        for (int g8 = 0; g8 < 4; ++g8)
            *(half8*)&dst[(c0 + 8 * g8) ^ sk] = *(const half8*)&Ks[k * KS_STRP + c0 + 8 * g8];
    }
    __syncthreads();

    // write Vth: stored[h][n ^ ((h&7)<<3)]
    {
        const int h  = tid >> 1;
        const int n0 = (tid & 1) * 32;
        const int th = (h & 7) << 3;
        _Float16* dst = wsh + KH_HALVES + (((size_t)b * NTILES + kt) * HH + h) * BN;
        #pragma unroll
        for (int g8 = 0; g8 < 4; ++g8)
            *(half8*)&dst[(n0 + 8 * g8) ^ th] = *(const half8*)&Vt[h * VT_STRP + n0 + 8 * g8];
    }
}

// ---------------------------------------------------------------------------
// main: flash split-K, transposed compute S^T/O^T. Tiles arrive via
// global_load_lds DMA from the pre-swizzled f16 workspace copies.
// ---------------------------------------------------------------------------
__launch_bounds__(256, 3)
__global__ void attn_main(const float* __restrict__ out_state,
                          const _Float16* __restrict__ wsh,
                          float* __restrict__ out,
                          char* __restrict__ wsb,
                          int splits) {
    __shared__ __align__(16) _Float16 Ks[BN * HH];        // 16 KB, rows swizzled
    __shared__ __align__(16) _Float16 Vt[HH * BN];        // 16 KB, rows swizzled
    __shared__ __align__(16) _Float16 Ps[4][16 * PS_STR]; // 9.2 KB per-wave P

    const int tid  = threadIdx.x;
    const int wave = tid >> 6;
    const int lane = tid & 63;
    const int quad = lane >> 4;
    const int lc   = lane & 15;
    const int swz  = (lc & 7) << 3;      // read-side XOR (row&7 == lc&7 everywhere)

    const int bid  = blockIdx.x;
    const int s    = bid >> 8;           // split id (grid = 256*splits)
    const int r256 = bid & 255;
    const int b    = r256 >> 5;
    const int qb   = r256 & 31;
    const int m0   = qb * BM;

    const int kt0 = (NTILES * s) / splits;
    const int kt1 = (NTILES * (s + 1)) / splits;

    const _Float16* khb = wsh + (size_t)b * KK * HH;                     // K rows (swizzled)
    const _Float16* vtb = wsh + KH_HALVES + (size_t)b * NTILES * (HH * BN); // K^T tiles

    // DMA: 16 KB tile = 16 chunks of 1 KB; wave w takes chunks {w, w+4, w+8, w+12}.
    auto issueK = [&](int t) {
        const char* gsrc = (const char*)(khb + (size_t)t * (BN * HH));
        #pragma unroll
        for (int c = 0; c < 4; ++c) {
            const int off = (c * 4 + wave) * 1024 + lane * 16;
            __builtin_amdgcn_global_load_lds((gvoid*)(gsrc + off),
                                             (lvoid*)((char*)Ks + off), 16, 0, 0);
        }
    };
    auto issueV = [&](int t) {
        const char* gsrc = (const char*)(vtb + (size_t)t * (HH * BN));
        #pragma unroll
        for (int c = 0; c < 4; ++c) {
            const int off = (c * 4 + wave) * 1024 + lane * 16;
            __builtin_amdgcn_global_load_lds((gvoid*)(gsrc + off),
                                             (lvoid*)((char*)Vt + off), 16, 0, 0);
        }
    };

    // kick off first tile's DMA, overlap with Q/tanh prologue
    issueK(kt0);
    issueV(kt0);

    // ---- Q fragment (MFMA B operand for S^T = K . Q^T)
    half8 qf[4];
    {
        const int m = m0 + wave * 16 + lc;
        const float* qrow = out_state + ((size_t)b * QQ + m) * HH;
        float4 qa[8];
        #pragma unroll
        for (int s4 = 0; s4 < 4; ++s4) {
            qa[2 * s4]     = *(const float4*)(qrow + 32 * s4 + quad * 8);
            qa[2 * s4 + 1] = *(const float4*)(qrow + 32 * s4 + quad * 8 + 4);
        }
        #pragma unroll
        for (int s4 = 0; s4 < 4; ++s4) {
            qf[s4][0] = (_Float16)tanhf(qa[2*s4].x);   qf[s4][1] = (_Float16)tanhf(qa[2*s4].y);
            qf[s4][2] = (_Float16)tanhf(qa[2*s4].z);   qf[s4][3] = (_Float16)tanhf(qa[2*s4].w);
            qf[s4][4] = (_Float16)tanhf(qa[2*s4+1].x); qf[s4][5] = (_Float16)tanhf(qa[2*s4+1].y);
            qf[s4][6] = (_Float16)tanhf(qa[2*s4+1].z); qf[s4][7] = (_Float16)tanhf(qa[2*s4+1].w);
        }
    }

    const f32x4 zero4 = {0.f, 0.f, 0.f, 0.f};
    f32x4 O[8];
    #pragma unroll
    for (int i = 0; i < 8; ++i) O[i] = zero4;
    f32x4 Osum = zero4;
    float rmax = -3.0e38f;

    const half8 ones = {(_Float16)1.f,(_Float16)1.f,(_Float16)1.f,(_Float16)1.f,
                        (_Float16)1.f,(_Float16)1.f,(_Float16)1.f,(_Float16)1.f};

    for (int kt = kt0; kt < kt1; ++kt) {
        const bool more = (kt + 1 < kt1);

        WAITVM4;        // own K-chunk DMAs for tile kt landed (V may still fly)
        wgbar();        // -> all waves' K chunks landed

        // ---- S^T = K . Q^T
        f32x4 S[4];
        __builtin_amdgcn_s_setprio(1);
        #pragma unroll
        for (int nt = 0; nt < 4; ++nt) {
            f32x4 acc = zero4;
            #pragma unroll
            for (int s4 = 0; s4 < 4; ++s4) {
                const half8 kf = *(const half8*)
                    &Ks[((nt * 16 + lc) << 7) + ((32 * s4 + (quad << 3)) ^ swz)];
                acc = __builtin_amdgcn_mfma_f32_16x16x32_f16(kf, qf[s4], acc, 0, 0, 0);
            }
            S[nt] = acc;
        }
        __builtin_amdgcn_s_setprio(0);

        wgbar();                    // all waves done reading Ks(kt)
        if (more) issueK(kt + 1);   // K(kt+1) DMA overlaps softmax + PV

        // ---- online softmax; rescale only when the running max actually grows
        float tmax = S[0][0];
        #pragma unroll
        for (int nt = 0; nt < 4; ++nt)
            #pragma unroll
            for (int r = 0; r < 4; ++r)
                tmax = fmaxf(tmax, S[nt][r]);
        tmax = fmaxf(tmax, __shfl_xor(tmax, 16, 64));
        tmax = fmaxf(tmax, __shfl_xor(tmax, 32, 64));

        if (!__all(tmax <= rmax)) {
            const float nm    = fmaxf(rmax, tmax);
            const float alpha = exp2f((rmax - nm) * L2E);
            rmax = nm;
            #pragma unroll
            for (int ct = 0; ct < 8; ++ct) O[ct] *= alpha;
            Osum *= alpha;
        }

        #pragma unroll
        for (int nt = 0; nt < 4; ++nt)
            #pragma unroll
            for (int r = 0; r < 4; ++r)
                S[nt][r] = exp2f((S[nt][r] - rmax) * L2E);

        #pragma unroll
        for (int nt = 0; nt < 4; ++nt) {
            half4 pv;
            pv[0] = (_Float16)S[nt][0]; pv[1] = (_Float16)S[nt][1];
            pv[2] = (_Float16)S[nt][2]; pv[3] = (_Float16)S[nt][3];
            *(half4*)&Ps[wave][lc * PS_STR + nt * 16 + quad * 4] = pv;
        }

        if (more) { WAITVM4; } else { WAITVM0; }   // V(kt) landed (K(kt+1) may fly)
        wgbar();

        // ---- O^T += V^T . P^T ; rowsum via ones-MFMA
        __builtin_amdgcn_s_setprio(1);
        #pragma unroll
        for (int s2 = 0; s2 < 2; ++s2) {
            const half8 pb = *(const half8*)&Ps[wave][lc * PS_STR + s2 * 32 + quad * 8];
            Osum = __builtin_amdgcn_mfma_f32_16x16x32_f16(ones, pb, Osum, 0, 0, 0);
            #pragma unroll
            for (int ct = 0; ct < 8; ++ct) {
                const half8 vf = *(const half8*)
                    &Vt[((ct * 16 + lc) << 6) + ((32 * s2 + (quad << 3)) ^ swz)];
                O[ct] = __builtin_amdgcn_mfma_f32_16x16x32_f16(vf, pb, O[ct], 0, 0, 0);
            }
        }
        __builtin_amdgcn_s_setprio(0);

        wgbar();                    // all waves done reading Vt(kt)
        if (more) issueV(kt + 1);
    }

    // ---- epilogue ----
    if (splits == 1) {
        const float inv = 1.0f / Osum[0];
        float* orow = out + ((size_t)b * QQ + m0 + wave * 16 + lc) * HH;
        #pragma unroll
        for (int ct = 0; ct < 8; ++ct) {
            f32x4 v = O[ct] * inv;
            *(f32x4*)&orow[ct * 16 + quad * 4] = v;
        }
    } else {
        // normalized f16 partials: O/l, combined later as sum(w*l*Onorm)/sum(w*l)
        const float inv = 1.0f / Osum[0];
        _Float16* oh = (_Float16*)(wsb + PREP_BYTES)
                     + ((size_t)(s * 256 + r256) * BM + wave * 16 + lc) * HH;
        #pragma unroll
        for (int ct = 0; ct < 8; ++ct) {
            const f32x4 v = O[ct] * inv;
            half4 hv;
            hv[0] = (_Float16)v[0]; hv[1] = (_Float16)v[1];
            hv[2] = (_Float16)v[2]; hv[3] = (_Float16)v[3];
            *(half4*)&oh[ct * 16 + quad * 4] = hv;
        }
        if (quad == 0) {
            float* wm = (float*)(wsb + PREP_BYTES + (size_t)splits * OSPLIT_BYTES);
            const size_t idx = (size_t)(s * 256 + r256) * BM + wave * 16 + lc;
            wm[idx] = rmax;
            wm[(size_t)splits * MLSPLIT_FLOATS + idx] = Osum[0];
        }
    }
}

__launch_bounds__(256)
__global__ void attn_combine(const char* __restrict__ wsb,
                             float* __restrict__ out,
                             int splits) {
    const int idx = blockIdx.x * 256 + threadIdx.x;   // over B*QQ*HH = 2^21
    const int h   = idx & 127;
    const int q   = (idx >> 7) & 2047;
    const int b   = idx >> 18;
    const int qb  = q >> 6;
    const int qr  = q & 63;
    const int blk = b * 32 + qb;

    const _Float16* oh = (const _Float16*)(wsb + PREP_BYTES);
    const float* wm = (const float*)(wsb + PREP_BYTES + (size_t)splits * OSPLIT_BYTES);
    const float* wl = wm + (size_t)splits * MLSPLIT_FLOATS;

    float ms[SPLITS_TARGET];
    float M = -3.0e38f;
    for (int s = 0; s < splits; ++s) {
        ms[s] = wm[(size_t)(s * 256 + blk) * BM + qr];
        M = fmaxf(M, ms[s]);
    }
    float denom = 0.f, val = 0.f;
    for (int s = 0; s < splits; ++s) {
        const float wgt = exp2f((ms[s] - M) * L2E) * wl[(size_t)(s * 256 + blk) * BM + qr];
        denom += wgt;
        val   += wgt * (float)oh[(size_t)(s * 256 + blk) * (BM * HH) + (size_t)qr * HH + h];
    }
    out[idx] = val / denom;
}

extern "C" void kernel_launch(void* const* d_in, const int* in_sizes, int n_in,
                              void* d_out, int out_size, void* d_ws, size_t ws_size,
                              hipStream_t stream) {
    const float* out_state = (const float*)d_in[0];
    const float* history   = (const float*)d_in[1];
    float* out = (float*)d_out;
    char* wsb  = (char*)d_ws;

    const size_t need3 = PREP_BYTES
                       + (size_t)SPLITS_TARGET * OSPLIT_BYTES
                       + (size_t)SPLITS_TARGET * 2 * MLSPLIT_FLOATS * 4;  // ~21.4 MB
    const int splits = (ws_size >= need3) ? SPLITS_TARGET : 1;

    attn_prep<<<dim3(256), dim3(256), 0, stream>>>(history, (_Float16*)wsb);
    attn_main<<<dim3(256 * splits), dim3(256), 0, stream>>>(out_state, (const _Float16*)wsb,
                                                            out, wsb, splits);
    if (splits > 1)
        attn_combine<<<dim3((8 * QQ * HH) / 256), dim3(256), 0, stream>>>(wsb, out, splits);
}